// Round 1
// baseline (3659.264 us; speedup 1.0000x reference)
//
#include <hip/hip_runtime.h>
#include <math.h>

#define T_SEQ 2048
#define C_DIM 2048
#define NH    16
#define NG    4
#define DH    128
#define BATCH 2

// ---------------------------------------------------------------------------
// C = A (M,K) @ B(N,K)^T  (+bias), fp32, 128x128 tile, BK=16, 8x8 microtile
// ---------------------------------------------------------------------------
__global__ __launch_bounds__(256)
void gemm_nt_f32(const float* __restrict__ A, const float* __restrict__ B,
                 const float* __restrict__ bias, float* __restrict__ C,
                 int M, int N, int K) {
    __shared__ float As[16][128];   // [k][row] transposed
    __shared__ float Bs[16][128];   // [k][col]
    const int t  = threadIdx.x;
    const int bm = blockIdx.y, bn = blockIdx.x;
    const int tx = t & 15, ty = t >> 4;

    float acc[8][8];
#pragma unroll
    for (int i = 0; i < 8; ++i)
#pragma unroll
        for (int j = 0; j < 8; ++j) acc[i][j] = 0.f;

    const float* Ap = A + (size_t)bm * 128 * K;
    const float* Bp = B + (size_t)bn * 128 * K;
    const int row0 = t >> 2;          // 0..63
    const int kq   = (t & 3) << 2;    // 0,4,8,12

    for (int k0 = 0; k0 < K; k0 += 16) {
#pragma unroll
        for (int r = 0; r < 2; ++r) {
            int row = row0 + r * 64;
            float4 av = *(const float4*)(Ap + (size_t)row * K + k0 + kq);
            float4 bv = *(const float4*)(Bp + (size_t)row * K + k0 + kq);
            As[kq+0][row] = av.x; As[kq+1][row] = av.y;
            As[kq+2][row] = av.z; As[kq+3][row] = av.w;
            Bs[kq+0][row] = bv.x; Bs[kq+1][row] = bv.y;
            Bs[kq+2][row] = bv.z; Bs[kq+3][row] = bv.w;
        }
        __syncthreads();
#pragma unroll
        for (int k = 0; k < 16; ++k) {
            float a[8], b[8];
            *(float4*)(a)   = *(const float4*)(&As[k][ty*8]);
            *(float4*)(a+4) = *(const float4*)(&As[k][ty*8+4]);
            *(float4*)(b)   = *(const float4*)(&Bs[k][tx*8]);
            *(float4*)(b+4) = *(const float4*)(&Bs[k][tx*8+4]);
#pragma unroll
            for (int i = 0; i < 8; ++i)
#pragma unroll
                for (int j = 0; j < 8; ++j)
                    acc[i][j] = fmaf(a[i], b[j], acc[i][j]);
        }
        __syncthreads();
    }

#pragma unroll
    for (int i = 0; i < 8; ++i) {
        int row = bm*128 + ty*8 + i;
#pragma unroll
        for (int j = 0; j < 8; j += 4) {
            int col = bn*128 + tx*8 + j;
            float4 v;
            v.x = acc[i][j+0]; v.y = acc[i][j+1];
            v.z = acc[i][j+2]; v.w = acc[i][j+3];
            if (bias) {
                v.x += bias[col+0]; v.y += bias[col+1];
                v.z += bias[col+2]; v.w += bias[col+3];
            }
            *(float4*)(C + (size_t)row * N + col) = v;
        }
    }
}

// ---------------------------------------------------------------------------
// In-place RMSNorm (per D=128 row) + RoPE. One wave per row; lane d owns
// elements d and d+64 (the rope pair). buf layout: (B*T*nheads, 128).
// ---------------------------------------------------------------------------
__global__ __launch_bounds__(256)
void rmsnorm_rope(float* __restrict__ buf, const float* __restrict__ w, int nheads) {
    const int row  = blockIdx.x * 4 + (threadIdx.x >> 6);
    const int lane = threadIdx.x & 63;
    float* p = buf + (size_t)row * 128;
    float x1 = p[lane], x2 = p[lane + 64];
    float ss = x1*x1 + x2*x2;
#pragma unroll
    for (int off = 32; off >= 1; off >>= 1) ss += __shfl_xor(ss, off, 64);
    float rms = sqrtf(ss * (1.0f/128.0f));
    float inv = 1.0f / (rms + 1e-6f);
    float x1n = w[lane]      * x1 * inv;
    float x2n = w[lane + 64] * x2 * inv;
    int tpos = (row / nheads) & (T_SEQ - 1);
    float invfreq = powf(10000.0f, -(float)lane / 64.0f);
    float ang = (float)tpos * invfreq;
    float s, c;
    sincosf(ang, &s, &c);
    p[lane]      = x1n * c + x2n * s;
    p[lane + 64] = x2n * c - x1n * s;
}

// ---------------------------------------------------------------------------
// Flash attention, causal, GQA, soft-cap 50. Block = 256 thr = 64 queries x
// 4 parts (each part owns 32 of the 128 dims, interleaved by float4 so LDS
// reads from the 4 parts hit disjoint banks). K/V 64x128 tiles in LDS.
// q layout (B,T,H,D); k,v layout (B,T,G,D); y layout (B,T,H*D).
// ---------------------------------------------------------------------------
__global__ __launch_bounds__(256)
void flash_attn(const float* __restrict__ q, const float* __restrict__ k,
                const float* __restrict__ v, float* __restrict__ y) {
    __shared__ float Ks[64 * 128];
    __shared__ float Vs[64 * 128];
    const int t  = threadIdx.x;
    const int q0 = blockIdx.x * 64;
    const int bh = blockIdx.y;
    const int b  = bh / NH, h = bh % NH;
    const int g  = h / (NH / NG);
    const int qi = t >> 2, part = t & 3;
    const float scale = 0.08838834764831845f;   // 1/sqrt(128)

    const float* qp = q + ((size_t)(b*T_SEQ + q0 + qi) * NH + h) * DH;
    float4 qr[8];
#pragma unroll
    for (int j = 0; j < 8; ++j) {
        float4 tv = *(const float4*)(qp + (j*4 + part) * 4);
        qr[j].x = tv.x * scale; qr[j].y = tv.y * scale;
        qr[j].z = tv.z * scale; qr[j].w = tv.w * scale;
    }
    float4 o[8];
#pragma unroll
    for (int j = 0; j < 8; ++j) o[j] = make_float4(0.f, 0.f, 0.f, 0.f);
    float m = -INFINITY, l = 0.f;

    for (int k0 = 0; k0 <= q0; k0 += 64) {
#pragma unroll
        for (int i = 0; i < 8; ++i) {
            int f    = i * 256 + t;        // float4 index 0..2047
            int krow = f >> 5;             // 0..63
            int c4   = (f & 31) << 2;      // 0..124
            size_t ga = ((size_t)(b*T_SEQ + k0 + krow) * NG + g) * DH + c4;
            *(float4*)&Ks[krow*128 + c4] = *(const float4*)(k + ga);
            *(float4*)&Vs[krow*128 + c4] = *(const float4*)(v + ga);
        }
        __syncthreads();

        for (int kk = 0; kk < 64; ++kk) {
            const float4* krow = (const float4*)&Ks[kk * 128];
            float s = 0.f;
#pragma unroll
            for (int j = 0; j < 8; ++j) {
                float4 kv = krow[j*4 + part];
                s = fmaf(qr[j].x, kv.x, s); s = fmaf(qr[j].y, kv.y, s);
                s = fmaf(qr[j].z, kv.z, s); s = fmaf(qr[j].w, kv.w, s);
            }
            s += __shfl_xor(s, 1, 64);
            s += __shfl_xor(s, 2, 64);
            bool valid = (k0 + kk) <= (q0 + qi);
            if (valid) {
                // 50*tanh(s/50) = 50 - 100/(exp(s*0.04)+1)
                float sc = 50.f - 100.f / (__expf(s * 0.04f) + 1.f);
                float mnew = fmaxf(m, sc);
                float corr = __expf(m - mnew);     // m=-inf on first key -> 0
                float p    = __expf(sc - mnew);
                l = l * corr + p;
                const float4* vrow = (const float4*)&Vs[kk * 128];
#pragma unroll
                for (int j = 0; j < 8; ++j) {
                    float4 vv = vrow[j*4 + part];
                    o[j].x = fmaf(o[j].x, corr, p * vv.x);
                    o[j].y = fmaf(o[j].y, corr, p * vv.y);
                    o[j].z = fmaf(o[j].z, corr, p * vv.z);
                    o[j].w = fmaf(o[j].w, corr, p * vv.w);
                }
                m = mnew;
            }
        }
        __syncthreads();
    }

    float invl = 1.f / l;
    float* yp = y + ((size_t)(b*T_SEQ + q0 + qi) * NH + h) * DH;
#pragma unroll
    for (int j = 0; j < 8; ++j) {
        float4 ov;
        ov.x = o[j].x * invl; ov.y = o[j].y * invl;
        ov.z = o[j].z * invl; ov.w = o[j].w * invl;
        *(float4*)(yp + (j*4 + part) * 4) = ov;
    }
}

// ---------------------------------------------------------------------------
extern "C" void kernel_launch(void* const* d_in, const int* in_sizes, int n_in,
                              void* d_out, int out_size, void* d_ws, size_t ws_size,
                              hipStream_t stream) {
    const float* x  = (const float*)d_in[0];
    const float* Wq = (const float*)d_in[1];
    const float* Wk = (const float*)d_in[2];
    const float* Wv = (const float*)d_in[3];
    const float* Wo = (const float*)d_in[4];
    const float* bo = (const float*)d_in[5];
    const float* qw = (const float*)d_in[6];
    const float* kw = (const float*)d_in[7];
    float* out = (float*)d_out;

    float* ws = (float*)d_ws;
    const size_t qElems = (size_t)BATCH * T_SEQ * NH * DH;   // 8,388,608
    const size_t kElems = (size_t)BATCH * T_SEQ * NG * DH;   // 2,097,152
    float* qb = ws;
    float* kb = qb + qElems;
    float* vb = kb + kElems;
    float* yb = vb + kElems;                                  // 8,388,608

    const int M = BATCH * T_SEQ;   // 4096
    dim3 blk(256);

    gemm_nt_f32<<<dim3(C_DIM/128, M/128), blk, 0, stream>>>(x, Wq, nullptr, qb, M, C_DIM, C_DIM);
    gemm_nt_f32<<<dim3((NG*DH)/128, M/128), blk, 0, stream>>>(x, Wk, nullptr, kb, M, NG*DH, C_DIM);
    gemm_nt_f32<<<dim3((NG*DH)/128, M/128), blk, 0, stream>>>(x, Wv, nullptr, vb, M, NG*DH, C_DIM);

    rmsnorm_rope<<<dim3(M * NH / 4), blk, 0, stream>>>(qb, qw, NH);
    rmsnorm_rope<<<dim3(M * NG / 4), blk, 0, stream>>>(kb, kw, NG);

    flash_attn<<<dim3(T_SEQ/64, BATCH*NH), blk, 0, stream>>>(qb, kb, vb, yb);

    gemm_nt_f32<<<dim3(C_DIM/128, M/128), blk, 0, stream>>>(yb, Wo, bo, out, M, C_DIM, C_DIM);
}

// Round 2
// 1769.575 us; speedup vs baseline: 2.0679x; 2.0679x over previous
//
#include <hip/hip_runtime.h>
#include <math.h>

#define T_SEQ 2048
#define C_DIM 2048
#define NH    16
#define NG    4
#define DH    128
#define BATCH 2

typedef __bf16 bf16_t;
typedef bf16_t bf16x8 __attribute__((ext_vector_type(8)));
typedef float  f32x4  __attribute__((ext_vector_type(4)));

static __device__ __forceinline__ unsigned short f2bf(float f) {
    return __builtin_bit_cast(unsigned short, (__bf16)f);
}

// ---------------------------------------------------------------------------
// C = A (M,K) @ B(N,K)^T  (+bias), fp32, 128x128 tile, BK=16, 8x8 microtile
// ---------------------------------------------------------------------------
__global__ __launch_bounds__(256)
void gemm_nt_f32(const float* __restrict__ A, const float* __restrict__ B,
                 const float* __restrict__ bias, float* __restrict__ C,
                 int M, int N, int K) {
    __shared__ float As[16][128];
    __shared__ float Bs[16][128];
    const int t  = threadIdx.x;
    const int bm = blockIdx.y, bn = blockIdx.x;
    const int tx = t & 15, ty = t >> 4;

    float acc[8][8];
#pragma unroll
    for (int i = 0; i < 8; ++i)
#pragma unroll
        for (int j = 0; j < 8; ++j) acc[i][j] = 0.f;

    const float* Ap = A + (size_t)bm * 128 * K;
    const float* Bp = B + (size_t)bn * 128 * K;
    const int row0 = t >> 2;
    const int kq   = (t & 3) << 2;

    for (int k0 = 0; k0 < K; k0 += 16) {
#pragma unroll
        for (int r = 0; r < 2; ++r) {
            int row = row0 + r * 64;
            float4 av = *(const float4*)(Ap + (size_t)row * K + k0 + kq);
            float4 bv = *(const float4*)(Bp + (size_t)row * K + k0 + kq);
            As[kq+0][row] = av.x; As[kq+1][row] = av.y;
            As[kq+2][row] = av.z; As[kq+3][row] = av.w;
            Bs[kq+0][row] = bv.x; Bs[kq+1][row] = bv.y;
            Bs[kq+2][row] = bv.z; Bs[kq+3][row] = bv.w;
        }
        __syncthreads();
#pragma unroll
        for (int k = 0; k < 16; ++k) {
            float a[8], b[8];
            *(float4*)(a)   = *(const float4*)(&As[k][ty*8]);
            *(float4*)(a+4) = *(const float4*)(&As[k][ty*8+4]);
            *(float4*)(b)   = *(const float4*)(&Bs[k][tx*8]);
            *(float4*)(b+4) = *(const float4*)(&Bs[k][tx*8+4]);
#pragma unroll
            for (int i = 0; i < 8; ++i)
#pragma unroll
                for (int j = 0; j < 8; ++j)
                    acc[i][j] = fmaf(a[i], b[j], acc[i][j]);
        }
        __syncthreads();
    }

#pragma unroll
    for (int i = 0; i < 8; ++i) {
        int row = bm*128 + ty*8 + i;
#pragma unroll
        for (int j = 0; j < 8; j += 4) {
            int col = bn*128 + tx*8 + j;
            float4 v;
            v.x = acc[i][j+0]; v.y = acc[i][j+1];
            v.z = acc[i][j+2]; v.w = acc[i][j+3];
            if (bias) {
                v.x += bias[col+0]; v.y += bias[col+1];
                v.z += bias[col+2]; v.w += bias[col+3];
            }
            *(float4*)(C + (size_t)row * N + col) = v;
        }
    }
}

// ---------------------------------------------------------------------------
// RMSNorm + RoPE, fp32 in -> bf16 out (optionally pre-scaled by `scale`).
// One wave per D=128 row; lane d owns the rope pair (d, d+64).
// ---------------------------------------------------------------------------
__global__ __launch_bounds__(256)
void rmsnorm_rope_cast(const float* __restrict__ in, const float* __restrict__ w,
                       unsigned short* __restrict__ out, int nheads, float scale) {
    const int row  = blockIdx.x * 4 + (threadIdx.x >> 6);
    const int lane = threadIdx.x & 63;
    const float* p = in + (size_t)row * 128;
    float x1 = p[lane], x2 = p[lane + 64];
    float ss = x1*x1 + x2*x2;
#pragma unroll
    for (int off = 32; off >= 1; off >>= 1) ss += __shfl_xor(ss, off, 64);
    float inv = 1.0f / (sqrtf(ss * (1.0f/128.0f)) + 1e-6f);
    float x1n = w[lane]      * x1 * inv;
    float x2n = w[lane + 64] * x2 * inv;
    int tpos = (row / nheads) & (T_SEQ - 1);
    float invfreq = powf(10000.0f, -(float)lane / 64.0f);
    float s, c;
    sincosf((float)tpos * invfreq, &s, &c);
    out[(size_t)row*128 + lane]      = f2bf((x1n * c + x2n * s) * scale);
    out[(size_t)row*128 + lane + 64] = f2bf((x2n * c - x1n * s) * scale);
}

// ---------------------------------------------------------------------------
// V cast fp32->bf16 + transpose: v (B,T,G,D) -> vt (B,G,D,T).
// Block handles one (b,g) x 64-t tile; LDS transpose (row pad 66 elems).
// ---------------------------------------------------------------------------
__global__ __launch_bounds__(256)
void v_cast_transpose(const float* __restrict__ v, unsigned short* __restrict__ vt) {
    __shared__ unsigned short Lt[128 * 66];
    const int t  = threadIdx.x;
    const int t0 = blockIdx.x * 64;
    const int bg = blockIdx.y;
    const int b  = bg / NG, g = bg % NG;
#pragma unroll
    for (int rep = 0; rep < 8; ++rep) {
        int idx = rep * 256 + t;        // 0..2047
        int i   = idx >> 5;             // t-row 0..63
        int c   = idx & 31;             // float4 col
        float4 f = *(const float4*)(v + ((size_t)(b*T_SEQ + t0 + i)*NG + g)*DH + c*4);
        Lt[(c*4+0)*66 + i] = f2bf(f.x);
        Lt[(c*4+1)*66 + i] = f2bf(f.y);
        Lt[(c*4+2)*66 + i] = f2bf(f.z);
        Lt[(c*4+3)*66 + i] = f2bf(f.w);
    }
    __syncthreads();
#pragma unroll
    for (int rep = 0; rep < 4; ++rep) {
        int idx = rep * 256 + t;        // 0..1023
        int d = idx >> 3, c = idx & 7;  // 8-elem chunk within 64-t row
        const unsigned short* src = &Lt[d*66 + c*8];
        unsigned int u0 = *(const unsigned int*)(src + 0);
        unsigned int u1 = *(const unsigned int*)(src + 2);
        unsigned int u2 = *(const unsigned int*)(src + 4);
        unsigned int u3 = *(const unsigned int*)(src + 6);
        uint4 val; val.x = u0; val.y = u1; val.z = u2; val.w = u3;
        *(uint4*)(vt + ((size_t)(bg*DH + d))*T_SEQ + t0 + c*8) = val;
    }
}

// ---------------------------------------------------------------------------
// MFMA flash attention (bf16 inputs, fp32 softmax/accum).
// Block = 4 waves; wave w owns 16 q-rows; K-tile = 64 keys.
// qh (B,T,H,D) bf16 pre-scaled by 1/sqrt(D); kh (B,T,G,D) bf16;
// vt (B,G,D,T) bf16; y (B,T,H*D) fp32.
// mfma_f32_16x16x32_bf16 layouts: A[m=lane&15][k=quad*8+j];
// C/D row=quad*4+reg, col=lane&15.
// ---------------------------------------------------------------------------
#define KPAD 136   // Ks row elems  (272 B rows: 16B-mult, bank step 4 -> 2-way)
#define VPAD 72    // Vts row elems (144 B rows)
#define PPAD 72    // Ps row elems

__global__ __launch_bounds__(256)
void flash_attn_mfma(const unsigned short* __restrict__ qh,
                     const unsigned short* __restrict__ kh,
                     const unsigned short* __restrict__ vt,
                     float* __restrict__ y) {
    __shared__ unsigned short Ks [64  * KPAD];
    __shared__ unsigned short Vts[128 * VPAD];
    __shared__ unsigned short Ps [64  * PPAD];   // 16 rows per wave

    const int t    = threadIdx.x;
    const int lane = t & 63, w = t >> 6;
    const int l15  = lane & 15, quad = lane >> 4;
    const int q0   = blockIdx.x * 64;
    const int bh   = blockIdx.y;
    const int b    = bh / NH, h = bh % NH;
    const int g    = h / (NH / NG);

    // Q fragments (A-operand), direct from global: row = q0 + w*16 + l15
    bf16x8 aq[4];
    const unsigned short* qp =
        qh + ((size_t)(b*T_SEQ + q0 + w*16 + l15) * NH + h) * DH;
#pragma unroll
    for (int kc = 0; kc < 4; ++kc)
        aq[kc] = __builtin_bit_cast(bf16x8, *(const uint4*)(qp + kc*32 + quad*8));

    f32x4 accO[8];
#pragma unroll
    for (int nd = 0; nd < 8; ++nd) accO[nd] = (f32x4){0.f, 0.f, 0.f, 0.f};
    float m_i[4], l_i[4];
#pragma unroll
    for (int r = 0; r < 4; ++r) { m_i[r] = -1e30f; l_i[r] = 0.f; }

    const int ktiles = q0 / 64 + 1;
    for (int kt = 0; kt < ktiles; ++kt) {
        const int k0 = kt * 64;
        // --- stage K tile: 64 rows x 128 bf16 (16 chunks of 16B per row) ---
#pragma unroll
        for (int rep = 0; rep < 4; ++rep) {
            int idx = rep * 256 + t;            // 0..1023
            int r = idx >> 4, c = idx & 15;
            *(uint4*)&Ks[r*KPAD + c*8] =
                *(const uint4*)(kh + ((size_t)(b*T_SEQ + k0 + r)*NG + g)*DH + c*8);
        }
        // --- stage V^T tile: 128 d-rows x 64 keys (8 chunks per row) ---
        const unsigned short* vbase = vt + ((size_t)(b*NG + g)*DH)*T_SEQ + k0;
#pragma unroll
        for (int rep = 0; rep < 4; ++rep) {
            int idx = rep * 256 + t;            // 0..1023
            int d = idx >> 3, c = idx & 7;
            *(uint4*)&Vts[d*VPAD + c*8] =
                *(const uint4*)(vbase + (size_t)d*T_SEQ + c*8);
        }
        __syncthreads();

        // --- S = Q K^T  (wave's 16x64 strip) ---
        f32x4 accS[4];
#pragma unroll
        for (int nt = 0; nt < 4; ++nt) accS[nt] = (f32x4){0.f, 0.f, 0.f, 0.f};
#pragma unroll
        for (int nt = 0; nt < 4; ++nt)
#pragma unroll
            for (int kc = 0; kc < 4; ++kc) {
                bf16x8 bk = __builtin_bit_cast(bf16x8,
                    *(const uint4*)&Ks[(nt*16 + l15)*KPAD + kc*32 + quad*8]);
                accS[nt] = __builtin_amdgcn_mfma_f32_16x16x32_bf16(aq[kc], bk, accS[nt], 0, 0, 0);
            }

        // --- soft-cap + causal mask + online softmax (rows = quad*4+reg) ---
        float p[4][4];   // [nt][reg]
#pragma unroll
        for (int r = 0; r < 4; ++r) {
            const int rowg = q0 + w*16 + quad*4 + r;
            float mx = -1e30f;
#pragma unroll
            for (int nt = 0; nt < 4; ++nt) {
                float s  = accS[nt][r];
                float sc = 50.f - 100.f / (__expf(s * 0.04f) + 1.f);
                int colg = k0 + nt*16 + l15;
                sc = (colg > rowg) ? -1e30f : sc;
                p[nt][r] = sc;
                mx = fmaxf(mx, sc);
            }
            mx = fmaxf(mx, __shfl_xor(mx, 1, 64));
            mx = fmaxf(mx, __shfl_xor(mx, 2, 64));
            mx = fmaxf(mx, __shfl_xor(mx, 4, 64));
            mx = fmaxf(mx, __shfl_xor(mx, 8, 64));
            float mnew = fmaxf(m_i[r], mx);
            float corr = __expf(m_i[r] - mnew);
            float rs = 0.f;
#pragma unroll
            for (int nt = 0; nt < 4; ++nt) {
                float pp = __expf(p[nt][r] - mnew);
                p[nt][r] = pp;
                rs += pp;
            }
            rs += __shfl_xor(rs, 1, 64);
            rs += __shfl_xor(rs, 2, 64);
            rs += __shfl_xor(rs, 4, 64);
            rs += __shfl_xor(rs, 8, 64);
            l_i[r] = l_i[r] * corr + rs;
            m_i[r] = mnew;
#pragma unroll
            for (int nd = 0; nd < 8; ++nd) accO[nd][r] *= corr;
        }

        // --- P: C-layout -> A-layout via per-wave LDS round-trip (bf16) ---
#pragma unroll
        for (int r = 0; r < 4; ++r)
#pragma unroll
            for (int nt = 0; nt < 4; ++nt)
                Ps[(w*16 + quad*4 + r)*PPAD + nt*16 + l15] = f2bf(p[nt][r]);

        bf16x8 ap[2];
#pragma unroll
        for (int kc = 0; kc < 2; ++kc)
            ap[kc] = __builtin_bit_cast(bf16x8,
                *(const uint4*)&Ps[(w*16 + l15)*PPAD + kc*32 + quad*8]);

        // --- O += P V  (B-operand from Vts: [d][key]) ---
#pragma unroll
        for (int nd = 0; nd < 8; ++nd)
#pragma unroll
            for (int kc = 0; kc < 2; ++kc) {
                bf16x8 bv = __builtin_bit_cast(bf16x8,
                    *(const uint4*)&Vts[(nd*16 + l15)*VPAD + kc*32 + quad*8]);
                accO[nd] = __builtin_amdgcn_mfma_f32_16x16x32_bf16(ap[kc], bv, accO[nd], 0, 0, 0);
            }
        __syncthreads();
    }

    // --- epilogue: divide by l, store fp32 y (B,T,H*D) ---
#pragma unroll
    for (int r = 0; r < 4; ++r) {
        float invl = 1.f / l_i[r];
        float* yp = y + (size_t)(b*T_SEQ + q0 + w*16 + quad*4 + r) * C_DIM + h*DH;
#pragma unroll
        for (int nd = 0; nd < 8; ++nd)
            yp[nd*16 + l15] = accO[nd][r] * invl;
    }
}

// ---------------------------------------------------------------------------
extern "C" void kernel_launch(void* const* d_in, const int* in_sizes, int n_in,
                              void* d_out, int out_size, void* d_ws, size_t ws_size,
                              hipStream_t stream) {
    const float* x  = (const float*)d_in[0];
    const float* Wq = (const float*)d_in[1];
    const float* Wk = (const float*)d_in[2];
    const float* Wv = (const float*)d_in[3];
    const float* Wo = (const float*)d_in[4];
    const float* bo = (const float*)d_in[5];
    const float* qw = (const float*)d_in[6];
    const float* kw = (const float*)d_in[7];
    float* out = (float*)d_out;

    const size_t qE = (size_t)BATCH * T_SEQ * NH * DH;   // 8M
    const size_t kE = (size_t)BATCH * T_SEQ * NG * DH;   // 2M
    float* qf = (float*)d_ws;
    float* kf = qf + qE;
    float* vf = kf + kE;
    unsigned short* qh  = (unsigned short*)(vf + kE);
    unsigned short* khb = qh + qE;
    unsigned short* vtb = khb + kE;
    float* yb = qf;   // q fp32 is dead after rmsnorm_rope_cast -> reuse for y

    const int M = BATCH * T_SEQ;   // 4096
    dim3 blk(256);

    gemm_nt_f32<<<dim3(C_DIM/128, M/128), blk, 0, stream>>>(x, Wq, nullptr, qf, M, C_DIM, C_DIM);
    gemm_nt_f32<<<dim3((NG*DH)/128, M/128), blk, 0, stream>>>(x, Wk, nullptr, kf, M, NG*DH, C_DIM);
    gemm_nt_f32<<<dim3((NG*DH)/128, M/128), blk, 0, stream>>>(x, Wv, nullptr, vf, M, NG*DH, C_DIM);

    rmsnorm_rope_cast<<<dim3(M * NH / 4), blk, 0, stream>>>(qf, qw, qh, NH, 0.08838834764831845f);
    rmsnorm_rope_cast<<<dim3(M * NG / 4), blk, 0, stream>>>(kf, kw, khb, NG, 1.0f);
    v_cast_transpose<<<dim3(T_SEQ/64, BATCH*NG), blk, 0, stream>>>(vf, vtb);

    flash_attn_mfma<<<dim3(T_SEQ/64, BATCH*NH), blk, 0, stream>>>(qh, khb, vtb, yb);

    gemm_nt_f32<<<dim3(C_DIM/128, M/128), blk, 0, stream>>>(yb, Wo, bo, out, M, C_DIM, C_DIM);
}

// Round 3
// 545.623 us; speedup vs baseline: 6.7066x; 3.2432x over previous
//
#include <hip/hip_runtime.h>
#include <math.h>

#define T_SEQ 2048
#define C_DIM 2048
#define NH    16
#define NG    4
#define DH    128
#define BATCH 2

typedef unsigned short u16;
typedef __bf16 bf16_t;
typedef bf16_t bf16x8 __attribute__((ext_vector_type(8)));
typedef float  f32x4  __attribute__((ext_vector_type(4)));

static __device__ __forceinline__ u16 f2bf(float f) {
    return __builtin_bit_cast(u16, (__bf16)f);
}

// async global->LDS, 16B per lane. lds must be wave-uniform base; HW adds lane*16.
static __device__ __forceinline__ void gll16(const void* g, void* lds) {
    __builtin_amdgcn_global_load_lds(
        (const __attribute__((address_space(1))) void*)(unsigned long long)(g),
        (__attribute__((address_space(3))) void*)(unsigned int)(unsigned long long)(lds),
        16, 0, 0);
}

// ---------------------------------------------------------------------------
// fp32 -> bf16 cast, 8 elems/thread
// ---------------------------------------------------------------------------
__global__ __launch_bounds__(256)
void cast_f32_bf16(const float* __restrict__ in, u16* __restrict__ out, int n8) {
    int i = blockIdx.x * 256 + threadIdx.x;
    if (i >= n8) return;
    const float4* p = (const float4*)in + (size_t)i * 2;
    float4 a = p[0], b = p[1];
    u16 u[8] = {f2bf(a.x), f2bf(a.y), f2bf(a.z), f2bf(a.w),
                f2bf(b.x), f2bf(b.y), f2bf(b.z), f2bf(b.w)};
    *(uint4*)(out + (size_t)i * 8) = *(const uint4*)u;
}

// ---------------------------------------------------------------------------
// C(fp32, M x N) = A_bf16(M,K) @ B_bf16(N,K)^T (+bias)
// 128x128 tile, BK=32, 4 waves, each wave 64x64 (4x4 MFMA 16x16x32).
// m97 structure: global_load_lds dwordx4 staging, no LDS padding.
// ---------------------------------------------------------------------------
static __device__ __forceinline__ void gemm_body(
        u16* As, u16* Bs,
        const u16* __restrict__ A, const u16* __restrict__ B,
        const float* __restrict__ bias, float* __restrict__ C,
        int N, int K, int m0, int n0) {
    const int t    = threadIdx.x;
    const int lane = t & 63, w = t >> 6;
    const int l15  = lane & 15, quad = lane >> 4;
    const int wr   = w >> 1, wc = w & 1;

    f32x4 acc[4][4];
#pragma unroll
    for (int mt = 0; mt < 4; ++mt)
#pragma unroll
        for (int nt = 0; nt < 4; ++nt) acc[mt][nt] = (f32x4){0.f, 0.f, 0.f, 0.f};

    // staging map: byte off = w*2048 + j*1024 + lane*16 ; row = off/64 (K-major
    // 32 bf16 = 64 B per row), col elem = (off%64)/2
    const int off0 = w*2048 + lane*16;
    const int r0 = off0 >> 6,          c0 = (off0 & 63) >> 1;
    const int r1 = (off0+1024) >> 6,   c1 = ((off0+1024) & 63) >> 1;
    const u16* Ag0 = A + (size_t)(m0 + r0) * K + c0;
    const u16* Ag1 = A + (size_t)(m0 + r1) * K + c1;
    const u16* Bg0 = B + (size_t)(n0 + r0) * K + c0;
    const u16* Bg1 = B + (size_t)(n0 + r1) * K + c1;
    char* AsB = (char*)As; char* BsB = (char*)Bs;
    const int ldsOff0 = w*2048, ldsOff1 = w*2048 + 1024;

    for (int k0 = 0; k0 < K; k0 += 32) {
        gll16(Ag0 + k0, AsB + ldsOff0);
        gll16(Ag1 + k0, AsB + ldsOff1);
        gll16(Bg0 + k0, BsB + ldsOff0);
        gll16(Bg1 + k0, BsB + ldsOff1);
        __syncthreads();
        bf16x8 af[4], bf[4];
#pragma unroll
        for (int mt = 0; mt < 4; ++mt)
            af[mt] = __builtin_bit_cast(bf16x8,
                *(const uint4*)&As[(wr*64 + mt*16 + l15)*32 + quad*8]);
#pragma unroll
        for (int nt = 0; nt < 4; ++nt)
            bf[nt] = __builtin_bit_cast(bf16x8,
                *(const uint4*)&Bs[(wc*64 + nt*16 + l15)*32 + quad*8]);
#pragma unroll
        for (int mt = 0; mt < 4; ++mt)
#pragma unroll
            for (int nt = 0; nt < 4; ++nt)
                acc[mt][nt] = __builtin_amdgcn_mfma_f32_16x16x32_bf16(
                                  af[mt], bf[nt], acc[mt][nt], 0, 0, 0);
        __syncthreads();
    }

#pragma unroll
    for (int mt = 0; mt < 4; ++mt)
#pragma unroll
        for (int nt = 0; nt < 4; ++nt) {
            const int col = n0 + wc*64 + nt*16 + l15;
            const float bv = bias ? bias[col] : 0.f;
#pragma unroll
            for (int r = 0; r < 4; ++r) {
                const int row = m0 + wr*64 + mt*16 + quad*4 + r;
                C[(size_t)row * N + col] = acc[mt][nt][r] + bv;
            }
        }
}

__global__ __launch_bounds__(256)
void gemm_nt_bf16(const u16* __restrict__ A, const u16* __restrict__ B,
                  const float* __restrict__ bias, float* __restrict__ C,
                  int N, int K) {
    __shared__ __align__(16) u16 As[128*32];
    __shared__ __align__(16) u16 Bs[128*32];
    gemm_body(As, Bs, A, B, bias, C, N, K, blockIdx.y*128, blockIdx.x*128);
}

__global__ __launch_bounds__(256)
void gemm_nt_bf16_kv(const u16* __restrict__ A,
                     const u16* __restrict__ Bk, const u16* __restrict__ Bv,
                     float* __restrict__ Ck, float* __restrict__ Cv,
                     int N, int K) {
    __shared__ __align__(16) u16 As[128*32];
    __shared__ __align__(16) u16 Bs[128*32];
    const u16* B = blockIdx.z ? Bv : Bk;
    float*     C = blockIdx.z ? Cv : Ck;
    gemm_body(As, Bs, A, B, nullptr, C, N, K, blockIdx.y*128, blockIdx.x*128);
}

// ---------------------------------------------------------------------------
// RMSNorm + RoPE, fp32 in -> bf16 out (pre-scaled by `scale`).
// ---------------------------------------------------------------------------
__global__ __launch_bounds__(256)
void rmsnorm_rope_cast(const float* __restrict__ in, const float* __restrict__ w,
                       u16* __restrict__ out, int nheads, float scale) {
    const int row  = blockIdx.x * 4 + (threadIdx.x >> 6);
    const int lane = threadIdx.x & 63;
    const float* p = in + (size_t)row * 128;
    float x1 = p[lane], x2 = p[lane + 64];
    float ss = x1*x1 + x2*x2;
#pragma unroll
    for (int off = 32; off >= 1; off >>= 1) ss += __shfl_xor(ss, off, 64);
    float inv = 1.0f / (sqrtf(ss * (1.0f/128.0f)) + 1e-6f);
    float x1n = w[lane]      * x1 * inv;
    float x2n = w[lane + 64] * x2 * inv;
    int tpos = (row / nheads) & (T_SEQ - 1);
    float invfreq = powf(10000.0f, -(float)lane / 64.0f);
    float s, c;
    sincosf((float)tpos * invfreq, &s, &c);
    out[(size_t)row*128 + lane]      = f2bf((x1n * c + x2n * s) * scale);
    out[(size_t)row*128 + lane + 64] = f2bf((x2n * c - x1n * s) * scale);
}

// ---------------------------------------------------------------------------
// V cast fp32->bf16 + transpose: v (B,T,G,D) -> vt (B,G,D,T).
// ---------------------------------------------------------------------------
__global__ __launch_bounds__(256)
void v_cast_transpose(const float* __restrict__ v, u16* __restrict__ vt) {
    __shared__ u16 Lt[128 * 66];
    const int t  = threadIdx.x;
    const int t0 = blockIdx.x * 64;
    const int bg = blockIdx.y;
    const int b  = bg / NG, g = bg % NG;
#pragma unroll
    for (int rep = 0; rep < 8; ++rep) {
        int idx = rep * 256 + t;
        int i   = idx >> 5;
        int c   = idx & 31;
        float4 f = *(const float4*)(v + ((size_t)(b*T_SEQ + t0 + i)*NG + g)*DH + c*4);
        Lt[(c*4+0)*66 + i] = f2bf(f.x);
        Lt[(c*4+1)*66 + i] = f2bf(f.y);
        Lt[(c*4+2)*66 + i] = f2bf(f.z);
        Lt[(c*4+3)*66 + i] = f2bf(f.w);
    }
    __syncthreads();
#pragma unroll
    for (int rep = 0; rep < 4; ++rep) {
        int idx = rep * 256 + t;
        int d = idx >> 3, c = idx & 7;
        const u16* src = &Lt[d*66 + c*8];
        uint4 val;
        val.x = *(const unsigned int*)(src + 0);
        val.y = *(const unsigned int*)(src + 2);
        val.z = *(const unsigned int*)(src + 4);
        val.w = *(const unsigned int*)(src + 6);
        *(uint4*)(vt + ((size_t)(bg*DH + d))*T_SEQ + t0 + c*8) = val;
    }
}

// ---------------------------------------------------------------------------
// MFMA flash attention (bf16 in, fp32 softmax/accum, bf16 y out).
// ---------------------------------------------------------------------------
#define KPAD 136
#define VPAD 72
#define PPAD 72

__global__ __launch_bounds__(256)
void flash_attn_mfma(const u16* __restrict__ qh, const u16* __restrict__ kh,
                     const u16* __restrict__ vt, u16* __restrict__ y) {
    __shared__ __align__(16) u16 Ks [64  * KPAD];
    __shared__ __align__(16) u16 Vts[128 * VPAD];
    __shared__ __align__(16) u16 Ps [64  * PPAD];

    const int t    = threadIdx.x;
    const int lane = t & 63, w = t >> 6;
    const int l15  = lane & 15, quad = lane >> 4;
    const int q0   = blockIdx.x * 64;
    const int bh   = blockIdx.y;
    const int b    = bh / NH, h = bh % NH;
    const int g    = h / (NH / NG);

    bf16x8 aq[4];
    const u16* qp = qh + ((size_t)(b*T_SEQ + q0 + w*16 + l15) * NH + h) * DH;
#pragma unroll
    for (int kc = 0; kc < 4; ++kc)
        aq[kc] = __builtin_bit_cast(bf16x8, *(const uint4*)(qp + kc*32 + quad*8));

    f32x4 accO[8];
#pragma unroll
    for (int nd = 0; nd < 8; ++nd) accO[nd] = (f32x4){0.f, 0.f, 0.f, 0.f};
    float m_i[4], l_i[4];
#pragma unroll
    for (int r = 0; r < 4; ++r) { m_i[r] = -1e30f; l_i[r] = 0.f; }

    const int ktiles = q0 / 64 + 1;
    for (int kt = 0; kt < ktiles; ++kt) {
        const int k0 = kt * 64;
#pragma unroll
        for (int rep = 0; rep < 4; ++rep) {
            int idx = rep * 256 + t;
            int r = idx >> 4, c = idx & 15;
            *(uint4*)&Ks[r*KPAD + c*8] =
                *(const uint4*)(kh + ((size_t)(b*T_SEQ + k0 + r)*NG + g)*DH + c*8);
        }
        const u16* vbase = vt + ((size_t)(b*NG + g)*DH)*T_SEQ + k0;
#pragma unroll
        for (int rep = 0; rep < 4; ++rep) {
            int idx = rep * 256 + t;
            int d = idx >> 3, c = idx & 7;
            *(uint4*)&Vts[d*VPAD + c*8] =
                *(const uint4*)(vbase + (size_t)d*T_SEQ + c*8);
        }
        __syncthreads();

        f32x4 accS[4];
#pragma unroll
        for (int nt = 0; nt < 4; ++nt) accS[nt] = (f32x4){0.f, 0.f, 0.f, 0.f};
#pragma unroll
        for (int nt = 0; nt < 4; ++nt)
#pragma unroll
            for (int kc = 0; kc < 4; ++kc) {
                bf16x8 bk = __builtin_bit_cast(bf16x8,
                    *(const uint4*)&Ks[(nt*16 + l15)*KPAD + kc*32 + quad*8]);
                accS[nt] = __builtin_amdgcn_mfma_f32_16x16x32_bf16(aq[kc], bk, accS[nt], 0, 0, 0);
            }

        float p[4][4];
#pragma unroll
        for (int r = 0; r < 4; ++r) {
            const int rowg = q0 + w*16 + quad*4 + r;
            float mx = -1e30f;
#pragma unroll
            for (int nt = 0; nt < 4; ++nt) {
                float s  = accS[nt][r];
                float sc = 50.f - 100.f / (__expf(s * 0.04f) + 1.f);
                int colg = k0 + nt*16 + l15;
                sc = (colg > rowg) ? -1e30f : sc;
                p[nt][r] = sc;
                mx = fmaxf(mx, sc);
            }
            mx = fmaxf(mx, __shfl_xor(mx, 1, 64));
            mx = fmaxf(mx, __shfl_xor(mx, 2, 64));
            mx = fmaxf(mx, __shfl_xor(mx, 4, 64));
            mx = fmaxf(mx, __shfl_xor(mx, 8, 64));
            float mnew = fmaxf(m_i[r], mx);
            float corr = __expf(m_i[r] - mnew);
            float rs = 0.f;
#pragma unroll
            for (int nt = 0; nt < 4; ++nt) {
                float pp = __expf(p[nt][r] - mnew);
                p[nt][r] = pp;
                rs += pp;
            }
            rs += __shfl_xor(rs, 1, 64);
            rs += __shfl_xor(rs, 2, 64);
            rs += __shfl_xor(rs, 4, 64);
            rs += __shfl_xor(rs, 8, 64);
            l_i[r] = l_i[r] * corr + rs;
            m_i[r] = mnew;
#pragma unroll
            for (int nd = 0; nd < 8; ++nd) accO[nd][r] *= corr;
        }

#pragma unroll
        for (int r = 0; r < 4; ++r)
#pragma unroll
            for (int nt = 0; nt < 4; ++nt)
                Ps[(w*16 + quad*4 + r)*PPAD + nt*16 + l15] = f2bf(p[nt][r]);

        bf16x8 ap[2];
#pragma unroll
        for (int kc = 0; kc < 2; ++kc)
            ap[kc] = __builtin_bit_cast(bf16x8,
                *(const uint4*)&Ps[(w*16 + l15)*PPAD + kc*32 + quad*8]);

#pragma unroll
        for (int nd = 0; nd < 8; ++nd)
#pragma unroll
            for (int kc = 0; kc < 2; ++kc) {
                bf16x8 bv = __builtin_bit_cast(bf16x8,
                    *(const uint4*)&Vts[(nd*16 + l15)*VPAD + kc*32 + quad*8]);
                accO[nd] = __builtin_amdgcn_mfma_f32_16x16x32_bf16(ap[kc], bv, accO[nd], 0, 0, 0);
            }
        __syncthreads();
    }

#pragma unroll
    for (int r = 0; r < 4; ++r) {
        float invl = 1.f / l_i[r];
        u16* yp = y + (size_t)(b*T_SEQ + q0 + w*16 + quad*4 + r) * C_DIM + h*DH;
#pragma unroll
        for (int nd = 0; nd < 8; ++nd)
            yp[nd*16 + l15] = f2bf(accO[nd][r] * invl);
    }
}

// ---------------------------------------------------------------------------
extern "C" void kernel_launch(void* const* d_in, const int* in_sizes, int n_in,
                              void* d_out, int out_size, void* d_ws, size_t ws_size,
                              hipStream_t stream) {
    const float* x  = (const float*)d_in[0];
    const float* Wq = (const float*)d_in[1];
    const float* Wk = (const float*)d_in[2];
    const float* Wv = (const float*)d_in[3];
    const float* Wo = (const float*)d_in[4];
    const float* bo = (const float*)d_in[5];
    const float* qw = (const float*)d_in[6];
    const float* kw = (const float*)d_in[7];
    float* out = (float*)d_out;

    const size_t qE = (size_t)BATCH * T_SEQ * NH * DH;   // 8,388,608
    const size_t kE = (size_t)BATCH * T_SEQ * NG * DH;   // 2,097,152
    const size_t wqE = (size_t)C_DIM * C_DIM;            // 4,194,304
    const size_t wkE = (size_t)(NG*DH) * C_DIM;          // 1,048,576

    float* qf  = (float*)d_ws;          // qE floats
    float* kf  = qf + qE;               // kE floats
    float* vf  = kf + kE;               // kE floats
    u16*   qh  = (u16*)(vf + kE);       // qE
    u16*   khb = qh + qE;               // kE
    u16*   vtb = khb + kE;              // kE
    u16*   xh  = vtb + kE;              // qE
    u16*   wqh = xh + qE;               // wqE
    u16*   wkh = wqh + wqE;             // wkE
    u16*   wvh = wkh + wkE;             // wkE
    u16*   woh = (u16*)kf;              // wqE (reuses kf: dead after rmsnorm_k)
    u16*   yh  = (u16*)qf;              // qE  (reuses qf: dead after rmsnorm_q)

    const int M = BATCH * T_SEQ;   // 4096
    dim3 blk(256);

    cast_f32_bf16<<<dim3(qE/8/256),  blk, 0, stream>>>(x,  xh,  qE/8);
    cast_f32_bf16<<<dim3(wqE/8/256), blk, 0, stream>>>(Wq, wqh, wqE/8);
    cast_f32_bf16<<<dim3(wkE/8/256), blk, 0, stream>>>(Wk, wkh, wkE/8);
    cast_f32_bf16<<<dim3(wkE/8/256), blk, 0, stream>>>(Wv, wvh, wkE/8);

    gemm_nt_bf16<<<dim3(C_DIM/128, M/128), blk, 0, stream>>>(xh, wqh, nullptr, qf, C_DIM, C_DIM);
    gemm_nt_bf16_kv<<<dim3((NG*DH)/128, M/128, 2), blk, 0, stream>>>(xh, wkh, wvh, kf, vf, NG*DH, C_DIM);

    rmsnorm_rope_cast<<<dim3(M * NH / 4), blk, 0, stream>>>(qf, qw, qh, NH, 0.08838834764831845f);
    rmsnorm_rope_cast<<<dim3(M * NG / 4), blk, 0, stream>>>(kf, kw, khb, NG, 1.0f);
    v_cast_transpose<<<dim3(T_SEQ/64, BATCH*NG), blk, 0, stream>>>(vf, vtb);

    // Wo cast placed after rmsnorm_k/v_transpose (woh overlays kf)
    cast_f32_bf16<<<dim3(wqE/8/256), blk, 0, stream>>>(Wo, woh, wqE/8);

    flash_attn_mfma<<<dim3(T_SEQ/64, BATCH*NH), blk, 0, stream>>>(qh, khb, vtb, yh);

    gemm_nt_bf16<<<dim3(C_DIM/128, M/128), blk, 0, stream>>>(yh, woh, bo, out, C_DIM, C_DIM);
}